// Round 8
// baseline (1765.123 us; speedup 1.0000x reference)
//
#include <hip/hip_runtime.h>
#include <math.h>

// AddrNet eval forward: B=524288, D_MODEL=128, HID=16, N_BINS=256, DEPTH=8.
// Round 8: same bit-exact arithmetic contract as PASSING R4-R7 (no-FMA
// separate mul/add roundings, k-ascending sums, bias-after, np-Cephes exp,
// mul-form silu, strict-> argmax). Mapping changes vs R7:
//   - __launch_bounds__(256, 2): empirically this toolchain caps VGPR at
//     256/min_waves -> arg 2 targets a 128-VGPR cap (R5/R6: arg4 -> 64 cap,
//     spills; R7: no arg -> 256 VGPRs, 1 wave/SIMD, latency-bound).
//   - bin loop unroll 4 -> 2: limits live W-tiles so ~90 live f32 fit in 128.
//   - v2f packed row pair retained (v_pk_mul_f32/v_pk_add_f32, bit-exact
//     per-element IEEE ops in unchanged order).

constexpr int BATCH  = 524288;
constexpr int DM     = 128;
constexpr int H      = 16;
constexpr int NB     = 256;
constexpr int DEPTHN = 8;

constexpr int BLOCK = 256;
constexpr int R     = 2;                    // rows per thread (packed)

typedef float v2f __attribute__((ext_vector_type(2)));

__device__ __forceinline__ float np_expf(float x) {
    // Replica of numpy's SIMD float32 exp (Cephes scheme). Explicit FMAs:
    // unaffected by fp-contract settings. MUST stay bit-identical to R4.
    const float LOG2E = 1.442695040888963407f;
    const float C1    = 0.693359375f;
    const float C2    = -2.12194440e-4f;
    float q = rintf(x * LOG2E);
    float r = __builtin_fmaf(q, -C1, x);
    r = __builtin_fmaf(q, -C2, r);
    float p = 1.9875691500E-4f;
    p = __builtin_fmaf(p, r, 1.3981999507E-3f);
    p = __builtin_fmaf(p, r, 8.3334519073E-3f);
    p = __builtin_fmaf(p, r, 4.1665795894E-2f);
    p = __builtin_fmaf(p, r, 1.6666665459E-1f);
    p = __builtin_fmaf(p, r, 5.0000001201E-1f);
    p = __builtin_fmaf(p, r * r, r);
    p = p + 1.0f;
    if (x > 88.72283935546875f)      return INFINITY;
    if (x < -103.97208404541015625f) return 0.0f;
    return ldexpf(p, (int)q);
}

__global__ __launch_bounds__(BLOCK, 2) void addrnet_r8_kernel(
    const float* __restrict__ x,      // [B,128]
    const float* __restrict__ W_in,   // [128,16]
    const float* __restrict__ b_in,   // [16]
    const float* __restrict__ embed,  // [256,16]
    const float* __restrict__ W_mlp,  // [16,16]
    const float* __restrict__ b_mlp,  // [16]
    const float* __restrict__ W_out,  // [16,256]
    const float* __restrict__ b_out,  // [256]
    int* __restrict__ out)            // [B,8] int32
{
#pragma clang fp contract(off)
    __shared__ __align__(16) float sEmb[NB * H];    // [bin][i]       16 KB
    __shared__ __align__(16) float sWoutT[NB * H];  // [j][k]         16 KB
    __shared__ __align__(16) float sWmlpT[H * H];   // [i][k]          1 KB
    __shared__ float sbmlp[H];
    __shared__ float sbout[NB];                     //                 1 KB

    for (int i = threadIdx.x; i < NB * H; i += BLOCK) sEmb[i] = embed[i];
    for (int i = threadIdx.x; i < H * NB; i += BLOCK) {
        int k = i / NB, j = i % NB;               // W_out[k][j] -> sWoutT[j][k]
        sWoutT[j * H + k] = W_out[i];
    }
    for (int i = threadIdx.x; i < H * H; i += BLOCK) {
        int k = i / H, j = i % H;                 // W_mlp[k][j] -> sWmlpT[j][k]
        sWmlpT[j * H + k] = W_mlp[i];
    }
    for (int i = threadIdx.x; i < H; i += BLOCK) sbmlp[i] = b_mlp[i];
    for (int i = threadIdx.x; i < NB; i += BLOCK) sbout[i] = b_out[i];
    __syncthreads();

    const int row0 = blockIdx.x * (BLOCK * R) + threadIdx.x;
    const int row1 = row0 + BLOCK;

    // ---- h = x @ W_in + b_in : mul rounded, then add; k ascending.
    //      W_in rows are wave-uniform global reads (s_load path). ----
    v2f h[H];
#pragma unroll
    for (int j = 0; j < H; ++j) h[j] = (v2f){0.0f, 0.0f};

    const float4* xr0 = reinterpret_cast<const float4*>(x + (size_t)row0 * DM);
    const float4* xr1 = reinterpret_cast<const float4*>(x + (size_t)row1 * DM);
    for (int k4 = 0; k4 < DM / 4; ++k4) {
        float4 v0 = xr0[k4];
        float4 v1 = xr1[k4];
        v2f px = {v0.x, v1.x};
        v2f py = {v0.y, v1.y};
        v2f pz = {v0.z, v1.z};
        v2f pw = {v0.w, v1.w};
        const float* w0 = &W_in[(k4 * 4 + 0) * H];
        const float* w1 = &W_in[(k4 * 4 + 1) * H];
        const float* w2 = &W_in[(k4 * 4 + 2) * H];
        const float* w3 = &W_in[(k4 * 4 + 3) * H];
#pragma unroll
        for (int j = 0; j < H; ++j) {
            v2f a = h[j];
            a = a + px * w0[j];    // packed: separate mul + add per element
            a = a + py * w1[j];
            a = a + pz * w2[j];
            a = a + pw * w3[j];
            h[j] = a;
        }
    }
#pragma unroll
    for (int j = 0; j < H; ++j) h[j] = h[j] + b_in[j];

    int* o0 = out + (size_t)row0 * DEPTHN;
    int* o1 = out + (size_t)row1 * DEPTHN;

    for (int d = 0; d < DEPTHN; ++d) {
        // ---- logits = h @ W_out + b_out ; argmax (first-index ties) ----
        float best0 = -INFINITY, best1 = -INFINITY;
        int bi0 = 0, bi1 = 0;
#pragma unroll 2
        for (int j = 0; j < NB; ++j) {
            const float4* w4 = reinterpret_cast<const float4*>(&sWoutT[j * H]);
            float4 wa = w4[0], wb = w4[1], wc = w4[2], wd = w4[3];
            const float w[16] = {wa.x, wa.y, wa.z, wa.w, wb.x, wb.y, wb.z, wb.w,
                                 wc.x, wc.y, wc.z, wc.w, wd.x, wd.y, wd.z, wd.w};
            v2f acc = {0.0f, 0.0f};
#pragma unroll
            for (int k = 0; k < H; ++k) acc = acc + h[k] * w[k];
            acc = acc + sbout[j];
            float a0 = acc.x, a1 = acc.y;
            bool c0 = a0 > best0;
            bi0   = c0 ? j  : bi0;
            best0 = c0 ? a0 : best0;
            bool c1 = a1 > best1;
            bi1   = c1 ? j  : bi1;
            best1 = c1 ? a1 : best1;
        }
        o0[d] = bi0;
        o1[d] = bi1;

        // ---- h = h + embed[bi] ----
        {
            const float4* e0 = reinterpret_cast<const float4*>(&sEmb[bi0 * H]);
            const float4* e1 = reinterpret_cast<const float4*>(&sEmb[bi1 * H]);
            float4 ea = e0[0], eb = e0[1], ec = e0[2], ed = e0[3];
            const float e0w[16] = {ea.x, ea.y, ea.z, ea.w, eb.x, eb.y, eb.z, eb.w,
                                   ec.x, ec.y, ec.z, ec.w, ed.x, ed.y, ed.z, ed.w};
            float4 fa = e1[0], fb = e1[1], fc = e1[2], fd = e1[3];
            const float e1w[16] = {fa.x, fa.y, fa.z, fa.w, fb.x, fb.y, fb.z, fb.w,
                                   fc.x, fc.y, fc.z, fc.w, fd.x, fd.y, fd.z, fd.w};
#pragma unroll
            for (int i = 0; i < H; ++i)
                h[i] = h[i] + (v2f){e0w[i], e1w[i]};
        }

        // ---- z = h @ W_mlp + b_mlp ; h = z * (1/(1+np_exp(-z))) ----
        v2f hn[H];
#pragma unroll
        for (int i = 0; i < H; ++i) {
            const float4* w4 = reinterpret_cast<const float4*>(&sWmlpT[i * H]);
            float4 wa = w4[0], wb = w4[1], wc = w4[2], wd = w4[3];
            const float w[16] = {wa.x, wa.y, wa.z, wa.w, wb.x, wb.y, wb.z, wb.w,
                                 wc.x, wc.y, wc.z, wc.w, wd.x, wd.y, wd.z, wd.w};
            v2f acc = {0.0f, 0.0f};
#pragma unroll
            for (int k = 0; k < H; ++k) acc = acc + h[k] * w[k];
            acc = acc + sbmlp[i];
            float a0 = acc.x, a1 = acc.y;
            float e0v = np_expf(-a0);
            float s0  = 1.0f / (1.0f + e0v);
            float e1v = np_expf(-a1);
            float s1  = 1.0f / (1.0f + e1v);
            hn[i] = (v2f){a0 * s0, a1 * s1};
        }
#pragma unroll
        for (int i = 0; i < H; ++i) h[i] = hn[i];
    }
}

extern "C" void kernel_launch(void* const* d_in, const int* in_sizes, int n_in,
                              void* d_out, int out_size, void* d_ws, size_t ws_size,
                              hipStream_t stream) {
    const float* x     = (const float*)d_in[0];
    const float* W_in  = (const float*)d_in[1];
    const float* b_in  = (const float*)d_in[2];
    const float* embed = (const float*)d_in[3];
    const float* W_mlp = (const float*)d_in[4];
    const float* b_mlp = (const float*)d_in[5];
    const float* W_out = (const float*)d_in[6];
    const float* b_out = (const float*)d_in[7];
    int* out = (int*)d_out;

    dim3 grid(BATCH / (BLOCK * R));   // 1024 blocks
    dim3 block(BLOCK);
    addrnet_r8_kernel<<<grid, block, 0, stream>>>(x, W_in, b_in, embed, W_mlp,
                                                  b_mlp, W_out, b_out, out);
}

// Round 9
// 1094.650 us; speedup vs baseline: 1.6125x; 1.6125x over previous
//
#include <hip/hip_runtime.h>
#include <math.h>

// AddrNet eval forward: B=524288, D_MODEL=128, HID=16, N_BINS=256, DEPTH=8.
// Round 9: same bit-exact arithmetic contract as PASSING R4-R8 (no-FMA
// separate mul/add roundings, k-ascending sums, bias-after, np-Cephes exp,
// mul-form silu, strict-> argmax). Mapping change: weights move to the
// SCALAR pipe. All W reads are wave-uniform -> s_load into SGPRs (0 VGPR,
// 0 LDS traffic). A prep kernel transposes W_out/W_mlp into d_ws so each
// bin's 16 weights are one contiguous s_load_dwordx16. LDS holds only the
// embed table (divergent gather). Live VGPRs ~90 -> fits 128 cap, no spill.

constexpr int BATCH  = 524288;
constexpr int DM     = 128;
constexpr int H      = 16;
constexpr int NB     = 256;
constexpr int DEPTHN = 8;

constexpr int BLOCK = 256;
constexpr int R     = 2;                    // rows per thread (packed v2f)

typedef float v2f __attribute__((ext_vector_type(2)));

__device__ __forceinline__ float np_expf(float x) {
    // Replica of numpy's SIMD float32 exp (Cephes scheme). Explicit FMAs:
    // unaffected by fp-contract settings. MUST stay bit-identical to R4.
    const float LOG2E = 1.442695040888963407f;
    const float C1    = 0.693359375f;
    const float C2    = -2.12194440e-4f;
    float q = rintf(x * LOG2E);
    float r = __builtin_fmaf(q, -C1, x);
    r = __builtin_fmaf(q, -C2, r);
    float p = 1.9875691500E-4f;
    p = __builtin_fmaf(p, r, 1.3981999507E-3f);
    p = __builtin_fmaf(p, r, 8.3334519073E-3f);
    p = __builtin_fmaf(p, r, 4.1665795894E-2f);
    p = __builtin_fmaf(p, r, 1.6666665459E-1f);
    p = __builtin_fmaf(p, r, 5.0000001201E-1f);
    p = __builtin_fmaf(p, r * r, r);
    p = p + 1.0f;
    if (x > 88.72283935546875f)      return INFINITY;
    if (x < -103.97208404541015625f) return 0.0f;
    return ldexpf(p, (int)q);
}

// ---- prep: transpose W_out [16][256] -> ws[0..4095] = WoutT [256][16]
//            and W_mlp [16][16] -> ws[4096..4351] = WmlpT [16][16] ----
__global__ void addrnet_prep_kernel(const float* __restrict__ W_out,
                                    const float* __restrict__ W_mlp,
                                    float* __restrict__ ws) {
    int t = threadIdx.x;                       // 256 threads, 1 block
    for (int i = t; i < NB * H; i += 256) {
        int j = i >> 4, k = i & 15;            // WoutT[j][k] = W_out[k][j]
        ws[j * H + k] = W_out[k * NB + j];
    }
    {
        int i = t >> 4, k = t & 15;            // WmlpT[i][k] = W_mlp[k][i]
        ws[NB * H + i * H + k] = W_mlp[k * H + i];
    }
}

__global__ __launch_bounds__(BLOCK, 2) void addrnet_r9_kernel(
    const float* __restrict__ x,      // [B,128]
    const float* __restrict__ W_in,   // [128,16]
    const float* __restrict__ b_in,   // [16]
    const float* __restrict__ embed,  // [256,16]
    const float* __restrict__ b_mlp,  // [16]
    const float* __restrict__ b_out,  // [256]
    const float* __restrict__ ws,     // WoutT[256][16] ++ WmlpT[16][16]
    int* __restrict__ out)            // [B,8] int32
{
#pragma clang fp contract(off)
    __shared__ __align__(16) float sEmb[NB * H];    // 16 KB, gather target

    for (int i = threadIdx.x; i < NB * H; i += BLOCK) sEmb[i] = embed[i];
    __syncthreads();

    const float* WoutT = ws;               // [j][k], contiguous per bin
    const float* WmlpT = ws + NB * H;      // [i][k]

    const int row0 = blockIdx.x * (BLOCK * R) + threadIdx.x;
    const int row1 = row0 + BLOCK;

    // ---- h = x @ W_in + b_in : mul rounded, then add; k ascending.
    //      W_in rows are wave-uniform global reads (s_load path). ----
    v2f h[H];
#pragma unroll
    for (int j = 0; j < H; ++j) h[j] = (v2f){0.0f, 0.0f};

    const float4* xr0 = reinterpret_cast<const float4*>(x + (size_t)row0 * DM);
    const float4* xr1 = reinterpret_cast<const float4*>(x + (size_t)row1 * DM);
    for (int k4 = 0; k4 < DM / 4; ++k4) {
        float4 v0 = xr0[k4];
        float4 v1 = xr1[k4];
        v2f px = {v0.x, v1.x};
        v2f py = {v0.y, v1.y};
        v2f pz = {v0.z, v1.z};
        v2f pw = {v0.w, v1.w};
        const float* w0 = &W_in[(k4 * 4 + 0) * H];
        const float* w1 = &W_in[(k4 * 4 + 1) * H];
        const float* w2 = &W_in[(k4 * 4 + 2) * H];
        const float* w3 = &W_in[(k4 * 4 + 3) * H];
#pragma unroll
        for (int j = 0; j < H; ++j) {
            v2f a = h[j];
            a = a + px * w0[j];    // scalar weight splat: per-element mul+add
            a = a + py * w1[j];
            a = a + pz * w2[j];
            a = a + pw * w3[j];
            h[j] = a;
        }
    }
#pragma unroll
    for (int j = 0; j < H; ++j) h[j] = h[j] + b_in[j];

    int* o0 = out + (size_t)row0 * DEPTHN;
    int* o1 = out + (size_t)row1 * DEPTHN;

    for (int d = 0; d < DEPTHN; ++d) {
        // ---- logits = h @ W_out + b_out ; argmax (first-index ties).
        //      Weights via uniform s_load (SGPR operands, no VGPR tile). ----
        float best0 = -INFINITY, best1 = -INFINITY;
        int bi0 = 0, bi1 = 0;
#pragma unroll 2
        for (int j = 0; j < NB; ++j) {
            const float* wr = &WoutT[j * H];
            v2f acc = {0.0f, 0.0f};
#pragma unroll
            for (int k = 0; k < H; ++k) acc = acc + h[k] * wr[k];
            acc = acc + b_out[j];
            float a0 = acc.x, a1 = acc.y;
            bool c0 = a0 > best0;
            bi0   = c0 ? j  : bi0;
            best0 = c0 ? a0 : best0;
            bool c1 = a1 > best1;
            bi1   = c1 ? j  : bi1;
            best1 = c1 ? a1 : best1;
        }
        o0[d] = bi0;
        o1[d] = bi1;

        // ---- h = h + embed[bi] (LDS gather, divergent) ----
        {
            const float4* e0 = reinterpret_cast<const float4*>(&sEmb[bi0 * H]);
            const float4* e1 = reinterpret_cast<const float4*>(&sEmb[bi1 * H]);
#pragma unroll
            for (int q4 = 0; q4 < 4; ++q4) {
                float4 ea = e0[q4];
                float4 eb = e1[q4];
                h[q4 * 4 + 0] = h[q4 * 4 + 0] + (v2f){ea.x, eb.x};
                h[q4 * 4 + 1] = h[q4 * 4 + 1] + (v2f){ea.y, eb.y};
                h[q4 * 4 + 2] = h[q4 * 4 + 2] + (v2f){ea.z, eb.z};
                h[q4 * 4 + 3] = h[q4 * 4 + 3] + (v2f){ea.w, eb.w};
            }
        }

        // ---- z = h @ W_mlp + b_mlp ; h = z * (1/(1+np_exp(-z))) ----
        v2f hn[H];
#pragma unroll
        for (int i = 0; i < H; ++i) {
            const float* wr = &WmlpT[i * H];
            v2f acc = {0.0f, 0.0f};
#pragma unroll
            for (int k = 0; k < H; ++k) acc = acc + h[k] * wr[k];
            acc = acc + b_mlp[i];
            float a0 = acc.x, a1 = acc.y;
            float e0v = np_expf(-a0);
            float s0  = 1.0f / (1.0f + e0v);
            float e1v = np_expf(-a1);
            float s1  = 1.0f / (1.0f + e1v);
            hn[i] = (v2f){a0 * s0, a1 * s1};
        }
#pragma unroll
        for (int i = 0; i < H; ++i) h[i] = hn[i];
    }
}

extern "C" void kernel_launch(void* const* d_in, const int* in_sizes, int n_in,
                              void* d_out, int out_size, void* d_ws, size_t ws_size,
                              hipStream_t stream) {
    const float* x     = (const float*)d_in[0];
    const float* W_in  = (const float*)d_in[1];
    const float* b_in  = (const float*)d_in[2];
    const float* embed = (const float*)d_in[3];
    const float* W_mlp = (const float*)d_in[4];
    const float* b_mlp = (const float*)d_in[5];
    const float* W_out = (const float*)d_in[6];
    const float* b_out = (const float*)d_in[7];
    int* out  = (int*)d_out;
    float* ws = (float*)d_ws;          // needs (4096+256)*4 = 17.4 KB

    addrnet_prep_kernel<<<1, 256, 0, stream>>>(W_out, W_mlp, ws);

    dim3 grid(BATCH / (BLOCK * R));    // 1024 blocks
    dim3 block(BLOCK);
    addrnet_r9_kernel<<<grid, block, 0, stream>>>(x, W_in, b_in, embed,
                                                  b_mlp, b_out, ws, out);
}